// Round 1
// baseline (4071.739 us; speedup 1.0000x reference)
//
#include <hip/hip_runtime.h>
#include <math.h>

// GRU: T=512, B=64, H=512, L=2. Single persistent fused kernel:
// 128 blocks = 64 layer-0 + 64 layer-1, layer-1 lagging one step (wavefront
// pipeline), 513 steps. Each block owns 8 hidden cols; 32 gate-rows = 8 cols
// x {r, z, n_x, n_h}. X-projection and H-dot are both MFMA (bf16), split
// accumulators (X/H) summed in the epilogue. Layer-0 X input = pre-transposed
// bf16 x (cached loads, issued BEFORE the flag wait); layer-1 X input =
// layer-0's published bf16 h (sc1 loads). h exchanged via relaxed agent-scope
// (sc1) 8B atomics in MFMA B-fragment order.
//
// Sync: NO atomic-tree barrier. Per-block monotone completion flags
// bar[2*blk+role] (plain sc1 stores after a wave-0 vmcnt(0) drain). Wave 0 of
// each block polls the 64 flag-pairs (one 8B load per lane) and ballots:
//   role 0 step s: all flags0 >= s  && all flags1 >= s-2   (h0 ring depth 4)
//   role 1 step s: all flags0 >= s  && all flags1 >= s
// h0buf is a 4-deep ring (slot s&3 holds h^(0)_s), h1buf stays 2-deep.
// Overwrite safety: slot (s+1)&3 last read at step s-3 by both layers, which
// is covered by flags0 >= s (own lockstep) and flags1 >= s-2 (cross slack).

typedef short bf16x8 __attribute__((ext_vector_type(8)));
typedef float f32x4 __attribute__((ext_vector_type(4)));

__device__ __forceinline__ unsigned short f2bf(float f) {
  unsigned u = __builtin_bit_cast(unsigned, f);
  return (unsigned short)((u + 0x7fff + ((u >> 16) & 1)) >> 16);
}
__device__ __forceinline__ unsigned long long ldq(const unsigned long long* p) {
  return __hip_atomic_load(p, __ATOMIC_RELAXED, __HIP_MEMORY_SCOPE_AGENT);
}
__device__ __forceinline__ void stq(unsigned long long* p,
                                    unsigned long long v) {
  __hip_atomic_store(p, v, __ATOMIC_RELAXED, __HIP_MEMORY_SCOPE_AGENT);
}
__device__ __forceinline__ void stw(unsigned* p, unsigned v) {
  __hip_atomic_store(p, v, __ATOMIC_RELAXED, __HIP_MEMORY_SCOPE_AGENT);
}

// fragment-order: element (k,b) -> chunk*8 + (k&7)
__device__ __forceinline__ int hchunk(int k, int b) {
  return ((b >> 4) * 16 + (k >> 5)) * 64 + ((k >> 3) & 3) * 16 + (b & 15);
}

// ---------------------------------------------------------------- prep
// h0buf slot0 / h1buf slot0 <- bf16(init) fragment order; zero flags.
// grid 128x512.
__global__ void gru_prep_h(const float* __restrict__ init,
                           unsigned short* __restrict__ h0buf,
                           unsigned short* __restrict__ h1buf,
                           unsigned* __restrict__ bar) {
  int l = blockIdx.x >> 6;
  int idx = (blockIdx.x & 63) * 512 + threadIdx.x;  // 0..32767
  int k = idx >> 6, b = idx & 63;
  unsigned short v = f2bf(init[(size_t)l * 32768 + b * 512 + k]);
  unsigned short* dst = (l == 0) ? h0buf : h1buf;
  dst[hchunk(k, b) * 8 + (k & 7)] = v;
  if (blockIdx.x == 0 && threadIdx.x < 512) bar[threadIdx.x] = 0u;
}

// ---------------------------------------------------------------- x transpose
// xbf[t][ck*8+e] = bf16(x[t][b][k]) in fragment order. grid 512(t) x 512.
__global__ void gru_xprep(const float* __restrict__ x,
                          unsigned short* __restrict__ xbf) {
  int t = blockIdx.x;
#pragma unroll
  for (int it = 0; it < 8; ++it) {
    int ck = it * 512 + threadIdx.x;  // 0..4095
    int b = (ck >> 10) * 16 + (ck & 15);
    int k0 = ((ck >> 6) & 15) * 32 + ((ck >> 4) & 3) * 8;
    const float* src = x + ((size_t)t * 64 + b) * 512 + k0;
    float4 v0 = *(const float4*)(src);
    float4 v1 = *(const float4*)(src + 4);
    unsigned short o[8] = {f2bf(v0.x), f2bf(v0.y), f2bf(v0.z), f2bf(v0.w),
                           f2bf(v1.x), f2bf(v1.y), f2bf(v1.z), f2bf(v1.w)};
    *(uint4*)(xbf + (size_t)t * 32768 + ck * 8) = *(const uint4*)o;
  }
}

// ---------------------------------------------------------------- weight images
// wX/wH[l][blk][row][k] bf16, row = c*4+q, col = blk*8+c.
// wX rows: q={Wir,Wiz,Win,0}; wH rows: q={Whr,Whz,0,Whn}. grid 128 x 256.
__global__ void gru_wimg(const float* __restrict__ Wir,
                         const float* __restrict__ Wiz,
                         const float* __restrict__ Win,
                         const float* __restrict__ Whr,
                         const float* __restrict__ Whz,
                         const float* __restrict__ Whn,
                         unsigned short* __restrict__ wX,
                         unsigned short* __restrict__ wH) {
  int l = blockIdx.x >> 6, blk = blockIdx.x & 63;
  size_t base = ((size_t)l * 64 + blk) * 32 * 512;
  size_t wbase = (size_t)l * 512 * 512;
  for (int idx = threadIdx.x; idx < 16384; idx += 256) {
    int c = idx & 7, k = (idx >> 3) & 511, q = idx >> 12;
    int col = blk * 8 + c;
    int row = c * 4 + q;
    size_t we = wbase + (size_t)k * 512 + col;
    float vx = 0.f, vh = 0.f;
    if (q == 0) { vx = Wir[we]; vh = Whr[we]; }
    else if (q == 1) { vx = Wiz[we]; vh = Whz[we]; }
    else if (q == 2) { vx = Win[we]; }
    else { vh = Whn[we]; }
    wX[base + (size_t)row * 512 + k] = f2bf(vx);
    wH[base + (size_t)row * 512 + k] = f2bf(vh);
  }
}

// ---------------------------------------------------------------- fused recurrence
// 128 blocks x 512 threads. role = blk>>6 (0: layer0, 1: layer1 lag-1).
// Wave wv: Nt = wv&3 (16-batch tile), Kh = wv>>2 (K half). A-frags in VGPRs.
__global__ __launch_bounds__(512, 2) void gru_recur_fused(
    const unsigned short* __restrict__ xbf,  // [512][32768]
    const unsigned short* __restrict__ wX,   // [2][64][32][512]
    const unsigned short* __restrict__ wH,
    const float* __restrict__ bir, const float* __restrict__ bhr,
    const float* __restrict__ biz, const float* __restrict__ bhz,
    const float* __restrict__ bin_, const float* __restrict__ bhn,
    const float* __restrict__ init,  // [2][64][512]
    unsigned short* h0buf,  // ring of 4 x 32768
    unsigned short* h1buf,  // ring of 2 x 32768
    float* __restrict__ Yout, float* __restrict__ finals, unsigned* bar) {
  __shared__ float ghp[2][32][66];          // [Kh][row][b]
  __shared__ unsigned short hpack[64 * 8];  // [b][c]
  const int tid = threadIdx.x;
  const int lane = tid & 63;
  const int wv = tid >> 6;  // 0..7
  const int Nt = wv & 3, Kh = wv >> 2;
  const int quad = lane >> 4, mm = lane & 15;
  const int role = blockIdx.x >> 6;  // block-uniform
  const int blk = blockIdx.x & 63;
  const int cg0 = blk * 8;
  const int c = wv, bb = lane;
  const int cg = cg0 + c;
  const float bR = bir[role * 512 + cg] + bhr[role * 512 + cg];
  const float bZ = biz[role * 512 + cg] + bhz[role * 512 + cg];
  const float bNX = bin_[role * 512 + cg];
  const float bNH = bhn[role * 512 + cg];

  // ---- A-fragments: X-image and H-image, 2 Mtiles x 8 Ksteps each
  bf16x8 aX0[8], aX1[8], aH0[8], aH1[8];
  {
    const unsigned short* wXb = wX + ((size_t)role * 64 + blk) * 32 * 512;
    const unsigned short* wHb = wH + ((size_t)role * 64 + blk) * 32 * 512;
#pragma unroll
    for (int j = 0; j < 8; ++j) {
      int ko = (Kh * 8 + j) * 32 + quad * 8;
      aX0[j] = *(const bf16x8*)(wXb + (size_t)mm * 512 + ko);
      aX1[j] = *(const bf16x8*)(wXb + (size_t)(16 + mm) * 512 + ko);
      aH0[j] = *(const bf16x8*)(wHb + (size_t)mm * 512 + ko);
      aH1[j] = *(const bf16x8*)(wHb + (size_t)(16 + mm) * 512 + ko);
    }
  }
  float hp = init[(size_t)role * 32768 + bb * 512 + cg];

  for (int s = 0; s <= 512; ++s) {
    const bool active = (role == 0) ? (s < 512) : (s >= 1);
    if (active) {
      const int t = (role == 0) ? s : s - 1;
      const unsigned long long* Xq =
          (const unsigned long long*)((role == 0)
                                          ? (xbf + (size_t)t * 32768)
                                          : (h0buf + (size_t)(s & 3) * 32768));
      const unsigned long long* Hq =
          (const unsigned long long*)((role == 0)
                                          ? (h0buf + (size_t)(s & 3) * 32768)
                                          : (h1buf + (size_t)(t & 1) * 32768));
      unsigned short* Hdst = (role == 0)
                                 ? (h0buf + (size_t)((s + 1) & 3) * 32768)
                                 : (h1buf + (size_t)((t + 1) & 1) * 32768);
      unsigned long long xq[16], hq[16];
      // ---- layer-0 X loads are static: issue BEFORE the flag wait so the
      // L2 latency overlaps detection latency.
      if (role == 0) {
#pragma unroll
        for (int j = 0; j < 8; ++j) {
          int base = ((Nt * 16 + Kh * 8 + j) * 64 + lane) << 1;
          xq[2 * j] = Xq[base];
          xq[2 * j + 1] = Xq[base + 1];
        }
      }
      // ---- flag wait: wave 0, lane l checks block-pair l of both layers
      if (wv == 0) {
        const int t_lo = s;                           // layer-0 flags
        const int t_hi = (role == 0) ? s - 2 : s;     // layer-1 flags
        const unsigned long long* fq = (const unsigned long long*)bar + lane;
        while (true) {
          unsigned long long pq = ldq(fq);
          bool ok = ((int)(unsigned)pq >= t_lo) &&
                    ((int)(unsigned)(pq >> 32) >= t_hi);
          if (__all(ok)) break;
        }
      }
      __syncthreads();
      // ---- B-fragment loads (all independent, in flight together)
#pragma unroll
      for (int j = 0; j < 8; ++j) {
        int base = ((Nt * 16 + Kh * 8 + j) * 64 + lane) << 1;
        if (role == 1) {  // sc1 (published h0)
          xq[2 * j] = ldq(Xq + base);
          xq[2 * j + 1] = ldq(Xq + base + 1);
        }
        hq[2 * j] = ldq(Hq + base);
        hq[2 * j + 1] = ldq(Hq + base + 1);
      }
      // ---- MFMA: split X/H accumulators (halves dependent-chain depth)
      f32x4 a0x = {0.f, 0.f, 0.f, 0.f}, a0h = {0.f, 0.f, 0.f, 0.f};
      f32x4 a1x = {0.f, 0.f, 0.f, 0.f}, a1h = {0.f, 0.f, 0.f, 0.f};
#pragma unroll
      for (int j = 0; j < 8; ++j) {
        union { unsigned long long q[2]; bf16x8 v; } ux, uh;
        ux.q[0] = xq[2 * j]; ux.q[1] = xq[2 * j + 1];
        uh.q[0] = hq[2 * j]; uh.q[1] = hq[2 * j + 1];
        a0x = __builtin_amdgcn_mfma_f32_16x16x32_bf16(aX0[j], ux.v, a0x, 0, 0, 0);
        a1x = __builtin_amdgcn_mfma_f32_16x16x32_bf16(aX1[j], ux.v, a1x, 0, 0, 0);
        a0h = __builtin_amdgcn_mfma_f32_16x16x32_bf16(aH0[j], uh.v, a0h, 0, 0, 0);
        a1h = __builtin_amdgcn_mfma_f32_16x16x32_bf16(aH1[j], uh.v, a1h, 0, 0, 0);
      }
      f32x4 acc0 = a0x + a0h, acc1 = a1x + a1h;
      // ---- D -> LDS (C/D: col=lane&15, row=quad*4+reg)
      {
        float* g = &ghp[Kh][0][0];
        int ncol = Nt * 16 + mm;
#pragma unroll
        for (int r = 0; r < 4; ++r) g[(quad * 4 + r) * 66 + ncol] = acc0[r];
#pragma unroll
        for (int r = 0; r < 4; ++r)
          g[(16 + quad * 4 + r) * 66 + ncol] = acc1[r];
      }
      __syncthreads();
      // ---- epilogue: thread owns (col c, batch bb)
      {
        float gr = ghp[0][c * 4 + 0][bb] + ghp[1][c * 4 + 0][bb];
        float gz = ghp[0][c * 4 + 1][bb] + ghp[1][c * 4 + 1][bb];
        float gnx = ghp[0][c * 4 + 2][bb] + ghp[1][c * 4 + 2][bb];
        float gnh = ghp[0][c * 4 + 3][bb] + ghp[1][c * 4 + 3][bb];
        float r = 1.0f / (1.0f + expf(-(gr + bR)));
        float z = 1.0f / (1.0f + expf(-(gz + bZ)));
        float n = tanhf(gnx + bNX + r * (gnh + bNH));
        float hnew = (1.0f - z) * n + z * hp;
        hp = hnew;
        hpack[bb * 8 + c] = f2bf(hnew);
        if (role == 1) {
          Yout[((size_t)t * 64 + bb) * 512 + cg] = hnew;
          if (t == 511) finals[32768 + bb * 512 + cg] = hnew;
        } else if (t == 511) {
          finals[bb * 512 + cg] = hnew;
        }
      }
      __syncthreads();
      // ---- publish new h (bf16 fragment order), wave 0; drain own stores
      // (wave 0 is the only wave with outstanding publish stores), then
      // store completion flag. No atomics, no tree.
      if (wv == 0) {
        int ck = ((lane >> 4) * 16 + (cg0 >> 5)) * 64 + ((cg0 >> 3) & 3) * 16 +
                 (lane & 15);
        const unsigned long long* src =
            (const unsigned long long*)(hpack + lane * 8);
        unsigned long long* dst = (unsigned long long*)(Hdst + (size_t)ck * 8);
        stq(dst, src[0]);
        stq(dst + 1, src[1]);
        asm volatile("s_waitcnt vmcnt(0)" ::: "memory");
        if (lane == 0) stw(bar + 2 * blk + role, (unsigned)(s + 1));
      }
    } else {
      // inactive edge steps (role1@s=0, role0@s=512) still advance the flag
      if (tid == 0) stw(bar + 2 * blk + role, (unsigned)(s + 1));
    }
  }
}

// ---------------------------------------------------------------- launch
extern "C" void kernel_launch(void* const* d_in, const int* in_sizes, int n_in,
                              void* d_out, int out_size, void* d_ws,
                              size_t ws_size, hipStream_t stream) {
  const float* x = (const float*)d_in[0];
  const float* init = (const float*)d_in[1];
  const float* w_ir = (const float*)d_in[2];
  const float* w_hr = (const float*)d_in[3];
  const float* w_iz = (const float*)d_in[4];
  const float* w_hz = (const float*)d_in[5];
  const float* w_in_ = (const float*)d_in[6];
  const float* w_hn = (const float*)d_in[7];
  const float* b_ir = (const float*)d_in[8];
  const float* b_hr = (const float*)d_in[9];
  const float* b_iz = (const float*)d_in[10];
  const float* b_hz = (const float*)d_in[11];
  const float* b_in_ = (const float*)d_in[12];
  const float* b_hn = (const float*)d_in[13];
  float* out = (float*)d_out;
  float* Y = out;                                // [T,B,H] = layer-1 outputs
  float* finals = out + (size_t)512 * 64 * 512;  // [L,B,H]

  // workspace layout (ushorts unless noted)
  unsigned short* xbf = (unsigned short*)d_ws;            // 512*32768
  unsigned short* wX = xbf + (size_t)512 * 32768;         // 2*64*32*512
  unsigned short* wH = wX + (size_t)2 * 64 * 32 * 512;
  unsigned short* h0buf = wH + (size_t)2 * 64 * 32 * 512; // 4*32768 (ring)
  unsigned short* h1buf = h0buf + (size_t)4 * 32768;      // 2*32768
  unsigned* bar = (unsigned*)(h1buf + 2 * 32768);         // 512 words

  gru_prep_h<<<128, 512, 0, stream>>>(init, h0buf, h1buf, bar);
  gru_xprep<<<512, 512, 0, stream>>>(x, xbf);
  gru_wimg<<<128, 256, 0, stream>>>(w_ir, w_iz, w_in_, w_hr, w_hz, w_hn, wX,
                                    wH);
  gru_recur_fused<<<128, 512, 0, stream>>>(
      xbf, wX, wH, b_ir, b_hr, b_iz, b_hz, b_in_, b_hn, init, h0buf, h1buf, Y,
      finals, bar);
}

// Round 2
// 3200.222 us; speedup vs baseline: 1.2723x; 1.2723x over previous
//
#include <hip/hip_runtime.h>
#include <math.h>

// GRU: T=512, B=64, H=512, L=2. Persistent fused kernel:
// 128 worker blocks (64 layer-0 + 64 layer-1, layer-1 lagging one step) +
// 1 dedicated aggregator block. 513 steps. Each worker block owns 8 hidden
// cols; 32 gate-rows = 8 cols x {r, z, n_x, n_h}. X-projection and H-dot are
// MFMA (bf16), split X/H accumulators. Layer-0 X input = pre-transposed bf16
// x (cached loads issued BEFORE the gen wait); layer-1 X input = layer-0's
// published bf16 h (sc1 loads). h exchanged via relaxed agent-scope 8B
// atomics in MFMA B-fragment order.
//
// Sync (round-2 design, post-mortem of the flag-poll storm):
//  - producers: after publish + wave-0 vmcnt(0) drain, ONE plain monotone
//    flag store bar[2*blk+role] = s+1. No RMW anywhere.
//  - fan-in: block 128 (aggregator, 1 wave) polls the 64 flag PAIRS (lane l
//    <-> block-pair l), wave-min-reduces both layers, publishes a single 8B
//    generation word {gen0,gen1} at bar[256]. Only poller with high rate.
//  - consumers: 1 lane per block polls the single gen word (broadcast line):
//      role 0 step s: gen0 >= s && gen1 >= s-2   (h0 ring depth 4)
//      role 1 step s: gen0 >= s && gen1 >= s
// h0buf = 4-deep ring (slot s&3 = h^(0)_s), h1buf = 2-deep ring.
// Overwrite safety: h0 slot (s+1)&3 last read at step s-3 (covered by
// gen0 >= s, gen1 >= s-2); h1 slot s&1 last read at step s-1 (gen1 >= s).

typedef short bf16x8 __attribute__((ext_vector_type(8)));
typedef float f32x4 __attribute__((ext_vector_type(4)));

__device__ __forceinline__ unsigned short f2bf(float f) {
  unsigned u = __builtin_bit_cast(unsigned, f);
  return (unsigned short)((u + 0x7fff + ((u >> 16) & 1)) >> 16);
}
__device__ __forceinline__ unsigned long long ldq(const unsigned long long* p) {
  return __hip_atomic_load(p, __ATOMIC_RELAXED, __HIP_MEMORY_SCOPE_AGENT);
}
__device__ __forceinline__ void stq(unsigned long long* p,
                                    unsigned long long v) {
  __hip_atomic_store(p, v, __ATOMIC_RELAXED, __HIP_MEMORY_SCOPE_AGENT);
}
__device__ __forceinline__ void stw(unsigned* p, unsigned v) {
  __hip_atomic_store(p, v, __ATOMIC_RELAXED, __HIP_MEMORY_SCOPE_AGENT);
}

// fragment-order: element (k,b) -> chunk*8 + (k&7)
__device__ __forceinline__ int hchunk(int k, int b) {
  return ((b >> 4) * 16 + (k >> 5)) * 64 + ((k >> 3) & 3) * 16 + (b & 15);
}

// ---------------------------------------------------------------- prep
// h0buf slot0 / h1buf slot0 <- bf16(init) fragment order; zero flags+gen.
// grid 128x512.
__global__ void gru_prep_h(const float* __restrict__ init,
                           unsigned short* __restrict__ h0buf,
                           unsigned short* __restrict__ h1buf,
                           unsigned* __restrict__ bar) {
  int l = blockIdx.x >> 6;
  int idx = (blockIdx.x & 63) * 512 + threadIdx.x;  // 0..32767
  int k = idx >> 6, b = idx & 63;
  unsigned short v = f2bf(init[(size_t)l * 32768 + b * 512 + k]);
  unsigned short* dst = (l == 0) ? h0buf : h1buf;
  dst[hchunk(k, b) * 8 + (k & 7)] = v;
  if (blockIdx.x == 0 && threadIdx.x < 512) bar[threadIdx.x] = 0u;
}

// ---------------------------------------------------------------- x transpose
// xbf[t][ck*8+e] = bf16(x[t][b][k]) in fragment order. grid 512(t) x 512.
__global__ void gru_xprep(const float* __restrict__ x,
                          unsigned short* __restrict__ xbf) {
  int t = blockIdx.x;
#pragma unroll
  for (int it = 0; it < 8; ++it) {
    int ck = it * 512 + threadIdx.x;  // 0..4095
    int b = (ck >> 10) * 16 + (ck & 15);
    int k0 = ((ck >> 6) & 15) * 32 + ((ck >> 4) & 3) * 8;
    const float* src = x + ((size_t)t * 64 + b) * 512 + k0;
    float4 v0 = *(const float4*)(src);
    float4 v1 = *(const float4*)(src + 4);
    unsigned short o[8] = {f2bf(v0.x), f2bf(v0.y), f2bf(v0.z), f2bf(v0.w),
                           f2bf(v1.x), f2bf(v1.y), f2bf(v1.z), f2bf(v1.w)};
    *(uint4*)(xbf + (size_t)t * 32768 + ck * 8) = *(const uint4*)o;
  }
}

// ---------------------------------------------------------------- weight images
// wX/wH[l][blk][row][k] bf16, row = c*4+q, col = blk*8+c.
// wX rows: q={Wir,Wiz,Win,0}; wH rows: q={Whr,Whz,0,Whn}. grid 128 x 256.
__global__ void gru_wimg(const float* __restrict__ Wir,
                         const float* __restrict__ Wiz,
                         const float* __restrict__ Win,
                         const float* __restrict__ Whr,
                         const float* __restrict__ Whz,
                         const float* __restrict__ Whn,
                         unsigned short* __restrict__ wX,
                         unsigned short* __restrict__ wH) {
  int l = blockIdx.x >> 6, blk = blockIdx.x & 63;
  size_t base = ((size_t)l * 64 + blk) * 32 * 512;
  size_t wbase = (size_t)l * 512 * 512;
  for (int idx = threadIdx.x; idx < 16384; idx += 256) {
    int c = idx & 7, k = (idx >> 3) & 511, q = idx >> 12;
    int col = blk * 8 + c;
    int row = c * 4 + q;
    size_t we = wbase + (size_t)k * 512 + col;
    float vx = 0.f, vh = 0.f;
    if (q == 0) { vx = Wir[we]; vh = Whr[we]; }
    else if (q == 1) { vx = Wiz[we]; vh = Whz[we]; }
    else if (q == 2) { vx = Win[we]; }
    else { vh = Whn[we]; }
    wX[base + (size_t)row * 512 + k] = f2bf(vx);
    wH[base + (size_t)row * 512 + k] = f2bf(vh);
  }
}

// ---------------------------------------------------------------- fused recurrence
// 129 blocks x 512 threads. Block 128 = aggregator (1 wave). Workers:
// role = blk>>6 (0: layer0, 1: layer1 lag-1). Wave wv: Nt = wv&3 (16-batch
// tile), Kh = wv>>2 (K half). A-frags in VGPRs.
__global__ __launch_bounds__(512, 2) void gru_recur_fused(
    const unsigned short* __restrict__ xbf,  // [512][32768]
    const unsigned short* __restrict__ wX,   // [2][64][32][512]
    const unsigned short* __restrict__ wH,
    const float* __restrict__ bir, const float* __restrict__ bhr,
    const float* __restrict__ biz, const float* __restrict__ bhz,
    const float* __restrict__ bin_, const float* __restrict__ bhn,
    const float* __restrict__ init,  // [2][64][512]
    unsigned short* h0buf,  // ring of 4 x 32768
    unsigned short* h1buf,  // ring of 2 x 32768
    float* __restrict__ Yout, float* __restrict__ finals, unsigned* bar) {
  // ---------------- aggregator block: fan-in flags -> single gen word
  if (blockIdx.x == 128) {
    if (threadIdx.x >= 64) return;
    const unsigned long long* fq =
        (const unsigned long long*)bar + threadIdx.x;  // pair for block l
    unsigned long long* genq = (unsigned long long*)(bar + 256);
    unsigned g0 = 0, g1 = 0;
    while (g0 < 513u || g1 < 513u) {
      unsigned long long pq = ldq(fq);
      unsigned f0 = (unsigned)pq, f1 = (unsigned)(pq >> 32);
#pragma unroll
      for (int m = 32; m; m >>= 1) {
        f0 = min(f0, (unsigned)__shfl_xor((int)f0, m));
        f1 = min(f1, (unsigned)__shfl_xor((int)f1, m));
      }
      if (f0 > g0 || f1 > g1) {
        g0 = f0;
        g1 = f1;
        if (threadIdx.x == 0)
          stq(genq, (unsigned long long)g0 | ((unsigned long long)g1 << 32));
      }
    }
    return;
  }

  __shared__ float ghp[2][32][66];          // [Kh][row][b]
  __shared__ unsigned short hpack[64 * 8];  // [b][c]
  const int tid = threadIdx.x;
  const int lane = tid & 63;
  const int wv = tid >> 6;  // 0..7
  const int Nt = wv & 3, Kh = wv >> 2;
  const int quad = lane >> 4, mm = lane & 15;
  const int role = blockIdx.x >> 6;  // block-uniform
  const int blk = blockIdx.x & 63;
  const int cg0 = blk * 8;
  const int c = wv, bb = lane;
  const int cg = cg0 + c;
  const float bR = bir[role * 512 + cg] + bhr[role * 512 + cg];
  const float bZ = biz[role * 512 + cg] + bhz[role * 512 + cg];
  const float bNX = bin_[role * 512 + cg];
  const float bNH = bhn[role * 512 + cg];

  // ---- A-fragments: X-image and H-image, 2 Mtiles x 8 Ksteps each
  bf16x8 aX0[8], aX1[8], aH0[8], aH1[8];
  {
    const unsigned short* wXb = wX + ((size_t)role * 64 + blk) * 32 * 512;
    const unsigned short* wHb = wH + ((size_t)role * 64 + blk) * 32 * 512;
#pragma unroll
    for (int j = 0; j < 8; ++j) {
      int ko = (Kh * 8 + j) * 32 + quad * 8;
      aX0[j] = *(const bf16x8*)(wXb + (size_t)mm * 512 + ko);
      aX1[j] = *(const bf16x8*)(wXb + (size_t)(16 + mm) * 512 + ko);
      aH0[j] = *(const bf16x8*)(wHb + (size_t)mm * 512 + ko);
      aH1[j] = *(const bf16x8*)(wHb + (size_t)(16 + mm) * 512 + ko);
    }
  }
  float hp = init[(size_t)role * 32768 + bb * 512 + cg];

  for (int s = 0; s <= 512; ++s) {
    const bool active = (role == 0) ? (s < 512) : (s >= 1);
    if (active) {
      const int t = (role == 0) ? s : s - 1;
      const unsigned long long* Xq =
          (const unsigned long long*)((role == 0)
                                          ? (xbf + (size_t)t * 32768)
                                          : (h0buf + (size_t)(s & 3) * 32768));
      const unsigned long long* Hq =
          (const unsigned long long*)((role == 0)
                                          ? (h0buf + (size_t)(s & 3) * 32768)
                                          : (h1buf + (size_t)(t & 1) * 32768));
      unsigned short* Hdst = (role == 0)
                                 ? (h0buf + (size_t)((s + 1) & 3) * 32768)
                                 : (h1buf + (size_t)((t + 1) & 1) * 32768);
      unsigned long long xq[16], hq[16];
      // ---- layer-0 X loads are static: issue BEFORE the gen wait so the
      // L2 latency overlaps detection latency.
      if (role == 0) {
#pragma unroll
        for (int j = 0; j < 8; ++j) {
          int base = ((Nt * 16 + Kh * 8 + j) * 64 + lane) << 1;
          xq[2 * j] = Xq[base];
          xq[2 * j + 1] = Xq[base + 1];
        }
      }
      // ---- gen wait: ONE lane polls the single broadcast gen word
      if (tid == 0) {
        const unsigned long long* genq =
            (const unsigned long long*)(bar + 256);
        const int need0 = s;
        const int need1 = (role == 0) ? s - 2 : s;
        while (true) {
          unsigned long long g = ldq(genq);
          if ((int)(unsigned)g >= need0 && (int)(unsigned)(g >> 32) >= need1)
            break;
        }
      }
      __syncthreads();
      // ---- B-fragment loads (all independent, in flight together)
#pragma unroll
      for (int j = 0; j < 8; ++j) {
        int base = ((Nt * 16 + Kh * 8 + j) * 64 + lane) << 1;
        if (role == 1) {  // sc1 (published h0)
          xq[2 * j] = ldq(Xq + base);
          xq[2 * j + 1] = ldq(Xq + base + 1);
        }
        hq[2 * j] = ldq(Hq + base);
        hq[2 * j + 1] = ldq(Hq + base + 1);
      }
      // ---- MFMA: split X/H accumulators (halves dependent-chain depth)
      f32x4 a0x = {0.f, 0.f, 0.f, 0.f}, a0h = {0.f, 0.f, 0.f, 0.f};
      f32x4 a1x = {0.f, 0.f, 0.f, 0.f}, a1h = {0.f, 0.f, 0.f, 0.f};
#pragma unroll
      for (int j = 0; j < 8; ++j) {
        union { unsigned long long q[2]; bf16x8 v; } ux, uh;
        ux.q[0] = xq[2 * j]; ux.q[1] = xq[2 * j + 1];
        uh.q[0] = hq[2 * j]; uh.q[1] = hq[2 * j + 1];
        a0x = __builtin_amdgcn_mfma_f32_16x16x32_bf16(aX0[j], ux.v, a0x, 0, 0, 0);
        a1x = __builtin_amdgcn_mfma_f32_16x16x32_bf16(aX1[j], ux.v, a1x, 0, 0, 0);
        a0h = __builtin_amdgcn_mfma_f32_16x16x32_bf16(aH0[j], uh.v, a0h, 0, 0, 0);
        a1h = __builtin_amdgcn_mfma_f32_16x16x32_bf16(aH1[j], uh.v, a1h, 0, 0, 0);
      }
      f32x4 acc0 = a0x + a0h, acc1 = a1x + a1h;
      // ---- D -> LDS (C/D: col=lane&15, row=quad*4+reg)
      {
        float* g = &ghp[Kh][0][0];
        int ncol = Nt * 16 + mm;
#pragma unroll
        for (int r = 0; r < 4; ++r) g[(quad * 4 + r) * 66 + ncol] = acc0[r];
#pragma unroll
        for (int r = 0; r < 4; ++r)
          g[(16 + quad * 4 + r) * 66 + ncol] = acc1[r];
      }
      __syncthreads();
      // ---- epilogue: thread owns (col c, batch bb)
      {
        float gr = ghp[0][c * 4 + 0][bb] + ghp[1][c * 4 + 0][bb];
        float gz = ghp[0][c * 4 + 1][bb] + ghp[1][c * 4 + 1][bb];
        float gnx = ghp[0][c * 4 + 2][bb] + ghp[1][c * 4 + 2][bb];
        float gnh = ghp[0][c * 4 + 3][bb] + ghp[1][c * 4 + 3][bb];
        float r = 1.0f / (1.0f + expf(-(gr + bR)));
        float z = 1.0f / (1.0f + expf(-(gz + bZ)));
        float n = tanhf(gnx + bNX + r * (gnh + bNH));
        float hnew = (1.0f - z) * n + z * hp;
        hp = hnew;
        hpack[bb * 8 + c] = f2bf(hnew);
        if (role == 1) {
          Yout[((size_t)t * 64 + bb) * 512 + cg] = hnew;
          if (t == 511) finals[32768 + bb * 512 + cg] = hnew;
        } else if (t == 511) {
          finals[bb * 512 + cg] = hnew;
        }
      }
      __syncthreads();
      // ---- publish new h (bf16 fragment order), wave 0; drain own stores
      // (wave 0 is the only wave with outstanding publish stores), then
      // store completion flag. No atomics, no tree.
      if (wv == 0) {
        int ck = ((lane >> 4) * 16 + (cg0 >> 5)) * 64 + ((cg0 >> 3) & 3) * 16 +
                 (lane & 15);
        const unsigned long long* src =
            (const unsigned long long*)(hpack + lane * 8);
        unsigned long long* dst = (unsigned long long*)(Hdst + (size_t)ck * 8);
        stq(dst, src[0]);
        stq(dst + 1, src[1]);
        asm volatile("s_waitcnt vmcnt(0)" ::: "memory");
        if (lane == 0) stw(bar + 2 * blk + role, (unsigned)(s + 1));
      }
    } else {
      // inactive edge steps (role1@s=0, role0@s=512) still advance the flag
      if (tid == 0) stw(bar + 2 * blk + role, (unsigned)(s + 1));
    }
  }
}

// ---------------------------------------------------------------- launch
extern "C" void kernel_launch(void* const* d_in, const int* in_sizes, int n_in,
                              void* d_out, int out_size, void* d_ws,
                              size_t ws_size, hipStream_t stream) {
  const float* x = (const float*)d_in[0];
  const float* init = (const float*)d_in[1];
  const float* w_ir = (const float*)d_in[2];
  const float* w_hr = (const float*)d_in[3];
  const float* w_iz = (const float*)d_in[4];
  const float* w_hz = (const float*)d_in[5];
  const float* w_in_ = (const float*)d_in[6];
  const float* w_hn = (const float*)d_in[7];
  const float* b_ir = (const float*)d_in[8];
  const float* b_hr = (const float*)d_in[9];
  const float* b_iz = (const float*)d_in[10];
  const float* b_hz = (const float*)d_in[11];
  const float* b_in_ = (const float*)d_in[12];
  const float* b_hn = (const float*)d_in[13];
  float* out = (float*)d_out;
  float* Y = out;                                // [T,B,H] = layer-1 outputs
  float* finals = out + (size_t)512 * 64 * 512;  // [L,B,H]

  // workspace layout (ushorts unless noted)
  unsigned short* xbf = (unsigned short*)d_ws;            // 512*32768
  unsigned short* wX = xbf + (size_t)512 * 32768;         // 2*64*32*512
  unsigned short* wH = wX + (size_t)2 * 64 * 32 * 512;
  unsigned short* h0buf = wH + (size_t)2 * 64 * 32 * 512; // 4*32768 (ring)
  unsigned short* h1buf = h0buf + (size_t)4 * 32768;      // 2*32768
  unsigned* bar = (unsigned*)(h1buf + 2 * 32768);         // 512 words

  gru_prep_h<<<128, 512, 0, stream>>>(init, h0buf, h1buf, bar);
  gru_xprep<<<512, 512, 0, stream>>>(x, xbf);
  gru_wimg<<<128, 256, 0, stream>>>(w_ir, w_iz, w_in_, w_hr, w_hz, w_hn, wX,
                                    wH);
  gru_recur_fused<<<129, 512, 0, stream>>>(
      xbf, wX, wH, b_ir, b_hr, b_iz, b_hz, b_in_, b_hn, init, h0buf, h1buf, Y,
      finals, bar);
}

// Round 3
// 2620.733 us; speedup vs baseline: 1.5537x; 1.2211x over previous
//
#include <hip/hip_runtime.h>
#include <math.h>

// GRU: T=512, B=64, H=512, L=2. Single persistent fused kernel:
// 128 blocks = 64 layer-0 + 64 layer-1, layer-1 lagging one step (wavefront
// pipeline), 513 grid-barrier steps total. Each block owns 8 hidden cols;
// 32 gate-rows = 8 cols x {r, z, n_x, n_h}. X-projection and H-dot are both
// MFMA (bf16), split X/H accumulators summed in the epilogue. Layer-0 X
// input = pre-transposed bf16 x (cached loads); layer-1 X input = layer-0's
// published bf16 h (sc1 loads). h exchanged via relaxed agent-scope (sc1)
// 8B atomics in MFMA B-fragment order; fp32 carry state in registers;
// monotone fence-free grid barrier (leaf/root atomic tree + s_sleep poll —
// measured better than flag-poll or aggregator alternatives, rounds 1-2).
//
// Round-3 fix: __launch_bounds__(512, 1). The previous (512,2) capped waves
// at 128 VGPRs while the A-fragments alone need 128 regs (total ~230) —
// the weight fragments were being spilled/reloaded through scratch every
// step. Grid is 128 blocks <= 256 CUs, so 1 block/CU was the real occupancy
// regardless; the ,2 bound bought nothing and cost a per-step reload.

typedef short bf16x8 __attribute__((ext_vector_type(8)));
typedef float f32x4 __attribute__((ext_vector_type(4)));

__device__ __forceinline__ unsigned short f2bf(float f) {
  unsigned u = __builtin_bit_cast(unsigned, f);
  return (unsigned short)((u + 0x7fff + ((u >> 16) & 1)) >> 16);
}
__device__ __forceinline__ unsigned long long ldq(const unsigned long long* p) {
  return __hip_atomic_load(p, __ATOMIC_RELAXED, __HIP_MEMORY_SCOPE_AGENT);
}
__device__ __forceinline__ void stq(unsigned long long* p,
                                    unsigned long long v) {
  __hip_atomic_store(p, v, __ATOMIC_RELAXED, __HIP_MEMORY_SCOPE_AGENT);
}

// fragment-order: element (k,b) -> chunk*8 + (k&7)
__device__ __forceinline__ int hchunk(int k, int b) {
  return ((b >> 4) * 16 + (k >> 5)) * 64 + ((k >> 3) & 3) * 16 + (b & 15);
}

// bar: leaf counters bar[leaf*32] (8 leaves x 16 blocks), root bar[256],
// gen bar[288]. All monotone; zeroed by prep each launch.
__device__ __forceinline__ void grid_barrier(unsigned* bar, unsigned target) {
  __syncthreads();  // drains vmcnt(0): sc1 stores globally visible
  if (threadIdx.x == 0) {
    unsigned leaf = blockIdx.x & 7u;
    unsigned prev = __hip_atomic_fetch_add(bar + leaf * 32, 1u,
                                           __ATOMIC_RELAXED,
                                           __HIP_MEMORY_SCOPE_AGENT);
    bool done = false;
    if ((prev & 15u) == 15u) {  // 16 blocks per leaf
      unsigned p2 = __hip_atomic_fetch_add(bar + 256, 1u, __ATOMIC_RELAXED,
                                           __HIP_MEMORY_SCOPE_AGENT);
      if ((p2 & 7u) == 7u) {
        __hip_atomic_store(bar + 288, target, __ATOMIC_RELAXED,
                           __HIP_MEMORY_SCOPE_AGENT);
        done = true;
      }
    }
    if (!done) {
      while (__hip_atomic_load(bar + 288, __ATOMIC_RELAXED,
                               __HIP_MEMORY_SCOPE_AGENT) < target) {
        __builtin_amdgcn_s_sleep(1);
      }
    }
  }
  __syncthreads();
}

// ---------------------------------------------------------------- prep
// h0buf[0]/h1buf[0] <- bf16(init) fragment order; zero barrier. grid 128x512.
__global__ void gru_prep_h(const float* __restrict__ init,
                           unsigned short* __restrict__ h0buf,
                           unsigned short* __restrict__ h1buf,
                           unsigned* __restrict__ bar) {
  int l = blockIdx.x >> 6;
  int idx = (blockIdx.x & 63) * 512 + threadIdx.x;  // 0..32767
  int k = idx >> 6, b = idx & 63;
  unsigned short v = f2bf(init[(size_t)l * 32768 + b * 512 + k]);
  unsigned short* dst = (l == 0) ? h0buf : h1buf;
  dst[hchunk(k, b) * 8 + (k & 7)] = v;
  if (blockIdx.x == 0 && threadIdx.x < 512) bar[threadIdx.x] = 0u;
}

// ---------------------------------------------------------------- x transpose
// xbf[t][ck*8+e] = bf16(x[t][b][k]) in fragment order. grid 512(t) x 512.
__global__ void gru_xprep(const float* __restrict__ x,
                          unsigned short* __restrict__ xbf) {
  int t = blockIdx.x;
#pragma unroll
  for (int it = 0; it < 8; ++it) {
    int ck = it * 512 + threadIdx.x;  // 0..4095
    int b = (ck >> 10) * 16 + (ck & 15);
    int k0 = ((ck >> 6) & 15) * 32 + ((ck >> 4) & 3) * 8;
    const float* src = x + ((size_t)t * 64 + b) * 512 + k0;
    float4 v0 = *(const float4*)(src);
    float4 v1 = *(const float4*)(src + 4);
    unsigned short o[8] = {f2bf(v0.x), f2bf(v0.y), f2bf(v0.z), f2bf(v0.w),
                           f2bf(v1.x), f2bf(v1.y), f2bf(v1.z), f2bf(v1.w)};
    *(uint4*)(xbf + (size_t)t * 32768 + ck * 8) = *(const uint4*)o;
  }
}

// ---------------------------------------------------------------- weight images
// wX/wH[l][blk][row][k] bf16, row = c*4+q, col = blk*8+c.
// wX rows: q={Wir,Wiz,Win,0}; wH rows: q={Whr,Whz,0,Whn}. grid 128 x 256.
__global__ void gru_wimg(const float* __restrict__ Wir,
                         const float* __restrict__ Wiz,
                         const float* __restrict__ Win,
                         const float* __restrict__ Whr,
                         const float* __restrict__ Whz,
                         const float* __restrict__ Whn,
                         unsigned short* __restrict__ wX,
                         unsigned short* __restrict__ wH) {
  int l = blockIdx.x >> 6, blk = blockIdx.x & 63;
  size_t base = ((size_t)l * 64 + blk) * 32 * 512;
  size_t wbase = (size_t)l * 512 * 512;
  for (int idx = threadIdx.x; idx < 16384; idx += 256) {
    int c = idx & 7, k = (idx >> 3) & 511, q = idx >> 12;
    int col = blk * 8 + c;
    int row = c * 4 + q;
    size_t we = wbase + (size_t)k * 512 + col;
    float vx = 0.f, vh = 0.f;
    if (q == 0) { vx = Wir[we]; vh = Whr[we]; }
    else if (q == 1) { vx = Wiz[we]; vh = Whz[we]; }
    else if (q == 2) { vx = Win[we]; }
    else { vh = Whn[we]; }
    wX[base + (size_t)row * 512 + k] = f2bf(vx);
    wH[base + (size_t)row * 512 + k] = f2bf(vh);
  }
}

// ---------------------------------------------------------------- fused recurrence
// 128 blocks x 512 threads. role = blk>>6 (0: layer0, 1: layer1 lag-1).
// Wave wv: Nt = wv&3 (16-batch tile), Kh = wv>>2 (K half). A-frags in VGPRs.
__global__ __launch_bounds__(512, 1) void gru_recur_fused(
    const unsigned short* __restrict__ xbf,  // [512][32768]
    const unsigned short* __restrict__ wX,   // [2][64][32][512]
    const unsigned short* __restrict__ wH,
    const float* __restrict__ bir, const float* __restrict__ bhr,
    const float* __restrict__ biz, const float* __restrict__ bhz,
    const float* __restrict__ bin_, const float* __restrict__ bhn,
    const float* __restrict__ init,  // [2][64][512]
    unsigned short* h0buf, unsigned short* h1buf,  // [2][32768] each
    float* __restrict__ Yout, float* __restrict__ finals, unsigned* bar) {
  __shared__ float ghp[2][32][66];          // [Kh][row][b]
  __shared__ unsigned short hpack[64 * 8];  // [b][c]
  const int tid = threadIdx.x;
  const int lane = tid & 63;
  const int wv = tid >> 6;  // 0..7
  const int Nt = wv & 3, Kh = wv >> 2;
  const int quad = lane >> 4, mm = lane & 15;
  const int role = blockIdx.x >> 6;  // block-uniform
  const int blk = blockIdx.x & 63;
  const int cg0 = blk * 8;
  const int c = wv, bb = lane;
  const int cg = cg0 + c;
  const float bR = bir[role * 512 + cg] + bhr[role * 512 + cg];
  const float bZ = biz[role * 512 + cg] + bhz[role * 512 + cg];
  const float bNX = bin_[role * 512 + cg];
  const float bNH = bhn[role * 512 + cg];

  // ---- A-fragments: X-image and H-image, 2 Mtiles x 8 Ksteps each
  bf16x8 aX0[8], aX1[8], aH0[8], aH1[8];
  {
    const unsigned short* wXb = wX + ((size_t)role * 64 + blk) * 32 * 512;
    const unsigned short* wHb = wH + ((size_t)role * 64 + blk) * 32 * 512;
#pragma unroll
    for (int j = 0; j < 8; ++j) {
      int ko = (Kh * 8 + j) * 32 + quad * 8;
      aX0[j] = *(const bf16x8*)(wXb + (size_t)mm * 512 + ko);
      aX1[j] = *(const bf16x8*)(wXb + (size_t)(16 + mm) * 512 + ko);
      aH0[j] = *(const bf16x8*)(wHb + (size_t)mm * 512 + ko);
      aH1[j] = *(const bf16x8*)(wHb + (size_t)(16 + mm) * 512 + ko);
    }
  }
  float hp = init[(size_t)role * 32768 + bb * 512 + cg];

  for (int s = 0; s <= 512; ++s) {
    const bool active = (role == 0) ? (s < 512) : (s >= 1);
    if (active) {
      const int t = (role == 0) ? s : s - 1;
      const unsigned long long* Xq =
          (const unsigned long long*)((role == 0)
                                          ? (xbf + (size_t)t * 32768)
                                          : (h0buf + (size_t)(s & 1) * 32768));
      const unsigned long long* Hq =
          (const unsigned long long*)((role == 0)
                                          ? (h0buf + (size_t)(s & 1) * 32768)
                                          : (h1buf + (size_t)(t & 1) * 32768));
      unsigned short* Hdst = (role == 0)
                                 ? (h0buf + (size_t)((s + 1) & 1) * 32768)
                                 : (h1buf + (size_t)((t + 1) & 1) * 32768);
      // ---- B-fragment loads (all independent, in flight together)
      unsigned long long xq[16], hq[16];
#pragma unroll
      for (int j = 0; j < 8; ++j) {
        int base = ((Nt * 16 + Kh * 8 + j) * 64 + lane) << 1;
        if (role == 0) {  // cached loads (static xbf)
          xq[2 * j] = Xq[base];
          xq[2 * j + 1] = Xq[base + 1];
        } else {  // sc1 (published h0)
          xq[2 * j] = ldq(Xq + base);
          xq[2 * j + 1] = ldq(Xq + base + 1);
        }
        hq[2 * j] = ldq(Hq + base);
        hq[2 * j + 1] = ldq(Hq + base + 1);
      }
      // ---- MFMA: split X/H accumulators (halves dependent-chain depth)
      f32x4 a0x = {0.f, 0.f, 0.f, 0.f}, a0h = {0.f, 0.f, 0.f, 0.f};
      f32x4 a1x = {0.f, 0.f, 0.f, 0.f}, a1h = {0.f, 0.f, 0.f, 0.f};
#pragma unroll
      for (int j = 0; j < 8; ++j) {
        union { unsigned long long q[2]; bf16x8 v; } ux, uh;
        ux.q[0] = xq[2 * j]; ux.q[1] = xq[2 * j + 1];
        uh.q[0] = hq[2 * j]; uh.q[1] = hq[2 * j + 1];
        a0x = __builtin_amdgcn_mfma_f32_16x16x32_bf16(aX0[j], ux.v, a0x, 0, 0, 0);
        a1x = __builtin_amdgcn_mfma_f32_16x16x32_bf16(aX1[j], ux.v, a1x, 0, 0, 0);
        a0h = __builtin_amdgcn_mfma_f32_16x16x32_bf16(aH0[j], uh.v, a0h, 0, 0, 0);
        a1h = __builtin_amdgcn_mfma_f32_16x16x32_bf16(aH1[j], uh.v, a1h, 0, 0, 0);
      }
      f32x4 acc0 = a0x + a0h, acc1 = a1x + a1h;
      // ---- D -> LDS (C/D: col=lane&15, row=quad*4+reg)
      {
        float* g = &ghp[Kh][0][0];
        int ncol = Nt * 16 + mm;
#pragma unroll
        for (int r = 0; r < 4; ++r) g[(quad * 4 + r) * 66 + ncol] = acc0[r];
#pragma unroll
        for (int r = 0; r < 4; ++r)
          g[(16 + quad * 4 + r) * 66 + ncol] = acc1[r];
      }
      __syncthreads();
      // ---- epilogue: thread owns (col c, batch bb)
      {
        float gr = ghp[0][c * 4 + 0][bb] + ghp[1][c * 4 + 0][bb];
        float gz = ghp[0][c * 4 + 1][bb] + ghp[1][c * 4 + 1][bb];
        float gnx = ghp[0][c * 4 + 2][bb] + ghp[1][c * 4 + 2][bb];
        float gnh = ghp[0][c * 4 + 3][bb] + ghp[1][c * 4 + 3][bb];
        float r = 1.0f / (1.0f + expf(-(gr + bR)));
        float z = 1.0f / (1.0f + expf(-(gz + bZ)));
        float n = tanhf(gnx + bNX + r * (gnh + bNH));
        float hnew = (1.0f - z) * n + z * hp;
        hp = hnew;
        hpack[bb * 8 + c] = f2bf(hnew);
        if (role == 1) {
          Yout[((size_t)t * 64 + bb) * 512 + cg] = hnew;
          if (t == 511) finals[32768 + bb * 512 + cg] = hnew;
        } else if (t == 511) {
          finals[bb * 512 + cg] = hnew;
        }
      }
      __syncthreads();
      // ---- publish new h (bf16 fragment order), wave 0
      if (tid < 64) {
        int ck = ((tid >> 4) * 16 + (cg0 >> 5)) * 64 + ((cg0 >> 3) & 3) * 16 +
                 (tid & 15);
        const unsigned long long* src =
            (const unsigned long long*)(hpack + tid * 8);
        unsigned long long* dst = (unsigned long long*)(Hdst + (size_t)ck * 8);
        stq(dst, src[0]);
        stq(dst + 1, src[1]);
      }
    }
    grid_barrier(bar, (unsigned)(s + 1));
  }
}

// ---------------------------------------------------------------- launch
extern "C" void kernel_launch(void* const* d_in, const int* in_sizes, int n_in,
                              void* d_out, int out_size, void* d_ws,
                              size_t ws_size, hipStream_t stream) {
  const float* x = (const float*)d_in[0];
  const float* init = (const float*)d_in[1];
  const float* w_ir = (const float*)d_in[2];
  const float* w_hr = (const float*)d_in[3];
  const float* w_iz = (const float*)d_in[4];
  const float* w_hz = (const float*)d_in[5];
  const float* w_in_ = (const float*)d_in[6];
  const float* w_hn = (const float*)d_in[7];
  const float* b_ir = (const float*)d_in[8];
  const float* b_hr = (const float*)d_in[9];
  const float* b_iz = (const float*)d_in[10];
  const float* b_hz = (const float*)d_in[11];
  const float* b_in_ = (const float*)d_in[12];
  const float* b_hn = (const float*)d_in[13];
  float* out = (float*)d_out;
  float* Y = out;                                // [T,B,H] = layer-1 outputs
  float* finals = out + (size_t)512 * 64 * 512;  // [L,B,H]

  // workspace layout (ushorts unless noted)
  unsigned short* xbf = (unsigned short*)d_ws;            // 512*32768
  unsigned short* wX = xbf + (size_t)512 * 32768;         // 2*64*32*512
  unsigned short* wH = wX + (size_t)2 * 64 * 32 * 512;
  unsigned short* h0buf = wH + (size_t)2 * 64 * 32 * 512; // 2*32768
  unsigned short* h1buf = h0buf + 2 * 32768;
  unsigned* bar = (unsigned*)(h1buf + 2 * 32768);         // 512 words

  gru_prep_h<<<128, 512, 0, stream>>>(init, h0buf, h1buf, bar);
  gru_xprep<<<512, 512, 0, stream>>>(x, xbf);
  gru_wimg<<<128, 256, 0, stream>>>(w_ir, w_iz, w_in_, w_hr, w_hz, w_hn, wX,
                                    wH);
  gru_recur_fused<<<128, 512, 0, stream>>>(
      xbf, wX, wH, b_ir, b_hr, b_iz, b_hz, b_in_, b_hn, init, h0buf, h1buf, Y,
      finals, bar);
}